// Round 5
// baseline (483.640 us; speedup 1.0000x reference)
//
#include <hip/hip_runtime.h>
#include <hip/hip_fp16.h>

#define N_NODES 50000
#define N_EDGES 800000
#define MID 25000            // src-range split for L2-blocked gather (3.2 MB halves)
#define HID 64
#define F_EDGE 16
#define LN_EPS 1e-5f
#define SCAN_BLOCKS ((N_NODES + 255) / 256)   // 196

typedef _Float16 h2n __attribute__((ext_vector_type(2)));
typedef float f4 __attribute__((ext_vector_type(4)));   // for nontemporal builtins

__device__ inline h2n to_n(__half2 v) {
    union { __half2 a; h2n b; } u; u.a = v; return u.b;
}
__device__ inline h2n pack2(float x, float y) {
    h2n r; r.x = (_Float16)x; r.y = (_Float16)y; return r;
}

// ---------------- utility: 64-lane wave reduction ----------------
__device__ inline float wave_sum64(float v) {
    #pragma unroll
    for (int o = 32; o > 0; o >>= 1) v += __shfl_xor(v, o, 64);
    return v;
}

// ---------------- CSR build ----------------
// packed count: low16 = total degree, high16 = edges with src < MID
__global__ void k_count(const int* __restrict__ src, const int* __restrict__ dst,
                        int* __restrict__ cnt) {
    int e = blockIdx.x * blockDim.x + threadIdx.x;
    if (e < N_EDGES) {
        int s = src[e], d = dst[e];
        atomicAdd(&cnt[d], (s < MID) ? 0x10001 : 1);
    }
}

// stage 1: per-block exclusive scan (over totals) into row_ptr, block sums into bsum; fused dinv
__global__ void k_scan1(const int* __restrict__ cnt, int* __restrict__ row_ptr,
                        int* __restrict__ bsum, float* __restrict__ dinv) {
    __shared__ int wsum[4];
    int tid = threadIdx.x, lane = tid & 63, w = tid >> 6;
    int i = blockIdx.x * 256 + tid;
    int v = (i < N_NODES) ? (cnt[i] & 0xffff) : 0;
    if (i < N_NODES) dinv[i] = rsqrtf((float)v + 1.0f);
    int isc = v;
    #pragma unroll
    for (int o = 1; o < 64; o <<= 1) {
        int n = __shfl_up(isc, o, 64);
        if (lane >= o) isc += n;
    }
    if (lane == 63) wsum[w] = isc;
    __syncthreads();
    int woff = 0;
    #pragma unroll
    for (int k = 0; k < 4; k++) woff += (k < w) ? wsum[k] : 0;
    if (i < N_NODES) row_ptr[i] = woff + isc - v;
    if (tid == 255) bsum[blockIdx.x] = woff + isc;
}

// stage 2 (+ decoder weight prep fused): single block
__global__ void k_scan2_prep(const int* __restrict__ bsum, int* __restrict__ boff,
                             const float* __restrict__ W1c, const float* __restrict__ W2,
                             __half2* __restrict__ w1cp, __half2* __restrict__ w2p) {
    __shared__ int wsum[4];
    int tid = threadIdx.x, lane = tid & 63, w = tid >> 6;
    int v = (tid < SCAN_BLOCKS) ? bsum[tid] : 0;
    int isc = v;
    #pragma unroll
    for (int o = 1; o < 64; o <<= 1) {
        int n = __shfl_up(isc, o, 64);
        if (lane >= o) isc += n;
    }
    if (lane == 63) wsum[w] = isc;
    __syncthreads();
    int woff = 0;
    #pragma unroll
    for (int k = 0; k < 4; k++) woff += (k < w) ? wsum[k] : 0;
    if (tid < SCAN_BLOCKS) boff[tid] = woff + isc - v;
    // ---- prep (independent of scan) ----
    for (int i = tid; i < 8 * 64; i += 256) {
        int k2 = i >> 6, j = i & 63;
        w1cp[i] = __floats2half2_rn(W1c[(2 * k2) * 64 + j], W1c[(2 * k2 + 1) * 64 + j]);
    }
    for (int i = tid; i < 32 * 32; i += 256) {
        int k2 = i >> 5, j = i & 31;
        w2p[i] = __floats2half2_rn(W2[(2 * k2) * 32 + j], W2[(2 * k2 + 1) * 32 + j]);
    }
}

// stage 3 (+ xs init fused): apply block offsets; init dual cursors + split; xs = fp16(dinv*x)
__global__ void k_scan3_xs(int* __restrict__ row_ptr, const int* __restrict__ boff,
                           const int* __restrict__ cnt,
                           int* __restrict__ cursor, int* __restrict__ cursor2,
                           int* __restrict__ split,
                           const float* __restrict__ x, const float* __restrict__ dinv,
                           __half* __restrict__ xs) {
    int i = blockIdx.x * blockDim.x + threadIdx.x;
    if (i < N_NODES) {
        int r = row_ptr[i] + boff[i >> 8];
        row_ptr[i] = r;
        cursor[i] = r;
        int sp = r + (cnt[i] >> 16);   // A-range (src<MID) occupies front of row
        split[i] = sp;
        cursor2[i] = sp;
    }
    if (i == 0) row_ptr[N_NODES] = N_EDGES;
    if (i < N_NODES * 64) xs[i] = __float2half_rn(x[i] * dinv[i >> 6]);
}

// fill: A-range edges (src<MID) at row front, B-range at back half
__global__ void k_fill(const int* __restrict__ src, const int* __restrict__ dst,
                       int* __restrict__ cursor, int* __restrict__ cursor2,
                       int* __restrict__ col) {
    int e = blockIdx.x * blockDim.x + threadIdx.x;
    if (e < N_EDGES) {
        int s = src[e], d = dst[e];
        int pos = (s < MID) ? atomicAdd(&cursor[d], 1)
                            : atomicAdd(&cursor2[d], 1);
        col[pos] = s;
    }
}

// ---------------- gather: L2-blocked, 2 passes ----------------
// pass 0: only edges with src <  MID (xs[0..MID)  = 3.2 MB, fits per-XCD L2);
//         writes RAW partial sums (nontemporal, no dinv).
// pass 1: only edges with src >= MID; reads partials back, adds, scales by dinv.
// Self-loop row handled in the pass owning its range. fp32 accum -> exact
// same arithmetic as single-pass, just reordered.
__device__ inline void row_acc(float4 raw, float m, float acc[8]) {
    const __half2* hp = (const __half2*)&raw;
    float2 f0 = __half22float2(hp[0]);
    float2 f1 = __half22float2(hp[1]);
    float2 f2 = __half22float2(hp[2]);
    float2 f3 = __half22float2(hp[3]);
    acc[0] = fmaf(f0.x, m, acc[0]); acc[1] = fmaf(f0.y, m, acc[1]);
    acc[2] = fmaf(f1.x, m, acc[2]); acc[3] = fmaf(f1.y, m, acc[3]);
    acc[4] = fmaf(f2.x, m, acc[4]); acc[5] = fmaf(f2.y, m, acc[5]);
    acc[6] = fmaf(f3.x, m, acc[6]); acc[7] = fmaf(f3.y, m, acc[7]);
}

__global__ void __launch_bounds__(256)
k_gather_agg(const __half* __restrict__ xs, const float* __restrict__ dinv,
             const int* __restrict__ row_ptr, const int* __restrict__ split,
             const int* __restrict__ col, float* __restrict__ agg, int pass) {
    int gid = blockIdx.x * blockDim.x + threadIdx.x;
    int n = gid >> 3;
    if (n >= N_NODES) return;
    int c8 = gid & 7;
    const float4* x4 = (const float4*)xs;

    int beg, end; bool self;
    if (pass == 0) { beg = row_ptr[n]; end = split[n];       self = (n <  MID); }
    else           { beg = split[n];   end = row_ptr[n + 1]; self = (n >= MID); }

    float acc[8];
    if (self) {   // self-loop row lives in this pass's src range
        float4 raw = x4[(size_t)n * 8 + c8];
        const __half2* hp = (const __half2*)&raw;
        float2 f0 = __half22float2(hp[0]);
        float2 f1 = __half22float2(hp[1]);
        float2 f2 = __half22float2(hp[2]);
        float2 f3 = __half22float2(hp[3]);
        acc[0] = f0.x; acc[1] = f0.y; acc[2] = f1.x; acc[3] = f1.y;
        acc[4] = f2.x; acc[5] = f2.y; acc[6] = f3.x; acc[7] = f3.y;
    } else {
        #pragma unroll
        for (int u = 0; u < 8; u++) acc[u] = 0.0f;
    }

    int t = beg;
    int s0 = 0, s1 = 0, s2 = 0, s3 = 0;
    if (t < end) {
        int e1 = end - 1;
        s0 = col[t];
        s1 = col[min(t + 1, e1)];
        s2 = col[min(t + 2, e1)];
        s3 = col[min(t + 3, e1)];
    }
    while (t < end) {
        float m1 = (t + 1 < end) ? 1.0f : 0.0f;
        float m2 = (t + 2 < end) ? 1.0f : 0.0f;
        float m3 = (t + 3 < end) ? 1.0f : 0.0f;
        float4 r0 = x4[(size_t)s0 * 8 + c8];
        float4 r1 = x4[(size_t)s1 * 8 + c8];
        float4 r2 = x4[(size_t)s2 * 8 + c8];
        float4 r3 = x4[(size_t)s3 * 8 + c8];
        t += 4;
        if (t < end) {            // prefetch next quad of col entries
            int e1 = end - 1;
            s0 = col[t];
            s1 = col[min(t + 1, e1)];
            s2 = col[min(t + 2, e1)];
            s3 = col[min(t + 3, e1)];
        }
        row_acc(r0, 1.0f, acc);   // slot 0 always valid (t_old < end)
        row_acc(r1, m1, acc);
        row_acc(r2, m2, acc);
        row_acc(r3, m3, acc);
    }

    f4* a4 = (f4*)agg;
    size_t base = (size_t)n * 16 + 2 * c8;
    if (pass == 0) {
        f4 y0, y1;
        y0.x = acc[0]; y0.y = acc[1]; y0.z = acc[2]; y0.w = acc[3];
        y1.x = acc[4]; y1.y = acc[5]; y1.z = acc[6]; y1.w = acc[7];
        __builtin_nontemporal_store(y0, &a4[base]);
        __builtin_nontemporal_store(y1, &a4[base + 1]);
    } else {
        f4 p0 = __builtin_nontemporal_load(&a4[base]);
        f4 p1 = __builtin_nontemporal_load(&a4[base + 1]);
        float di = dinv[n];
        f4 y0, y1;
        y0.x = (acc[0] + p0.x) * di; y0.y = (acc[1] + p0.y) * di;
        y0.z = (acc[2] + p0.z) * di; y0.w = (acc[3] + p0.w) * di;
        y1.x = (acc[4] + p1.x) * di; y1.y = (acc[5] + p1.y) * di;
        y1.z = (acc[6] + p1.z) * di; y1.w = (acc[7] + p1.w) * di;
        a4[base] = y0;
        a4[base + 1] = y1;
    }
}

// ---------------- fused: y = relu(LN(agg @ W + cb)); out fp16 xs or fp32 h ----------------
__global__ void __launch_bounds__(256)
k_gemm_ln(const float* __restrict__ agg, const float* __restrict__ W,
          const float* __restrict__ cb, const float* __restrict__ g,
          const float* __restrict__ b, const float* __restrict__ dinv,
          __half* __restrict__ xs_out, float* __restrict__ h_out) {
    int lane = threadIdx.x & 63;
    int wid = (blockIdx.x * blockDim.x + threadIdx.x) >> 6;
    int nwaves = (gridDim.x * blockDim.x) >> 6;
    float w[64];
    #pragma unroll
    for (int k = 0; k < 64; k++) w[k] = W[k * 64 + lane];
    float cbl = cb[lane], gl = g[lane], bl = b[lane];
    for (int row = wid; row < N_NODES; row += nwaves) {
        int r = __builtin_amdgcn_readfirstlane(row);
        const float* xr = agg + r * 64;
        float acc = cbl;
        #pragma unroll
        for (int k = 0; k < 64; k++) acc = fmaf(xr[k], w[k], acc);
        float mu = wave_sum64(acc) * (1.0f / 64.0f);
        float d = acc - mu;
        float var = wave_sum64(d * d) * (1.0f / 64.0f);
        float y = fmaxf(fmaf(d * rsqrtf(var + LN_EPS), gl, bl), 0.0f);
        if (xs_out) {
            xs_out[r * 64 + lane] = __float2half_rn(y * dinv[r]);
        } else {
            h_out[r * 64 + lane] = y;
        }
    }
}

// fused P/Q (fp16 out): first half of blocks -> P = h@W1a + b1, second half -> Q = h@W1b
__global__ void __launch_bounds__(256)
k_gemm_pq(const float* __restrict__ hin, const float* __restrict__ Wp,
          const float* __restrict__ bp, const float* __restrict__ Wq,
          __half* __restrict__ P, __half* __restrict__ Q) {
    int half_g = gridDim.x >> 1;
    bool isQ = (blockIdx.x >= half_g);
    const float* W = isQ ? Wq : Wp;
    __half* out = isQ ? Q : P;
    int lane = threadIdx.x & 63;
    int bid = isQ ? (blockIdx.x - half_g) : blockIdx.x;
    int wid = (bid * blockDim.x + threadIdx.x) >> 6;
    int nwaves = (half_g * blockDim.x) >> 6;
    float w[64];
    #pragma unroll
    for (int k = 0; k < 64; k++) w[k] = W[k * 64 + lane];
    float binit = isQ ? 0.0f : bp[lane];
    for (int row = wid; row < N_NODES; row += nwaves) {
        int r = __builtin_amdgcn_readfirstlane(row);
        const float* xr = hin + r * 64;
        float acc = binit;
        #pragma unroll
        for (int k = 0; k < 64; k++) acc = fmaf(xr[k], w[k], acc);
        out[r * 64 + lane] = __float2half_rn(acc);
    }
}

// ---------------- decoder: edge order; fp16 P/Q; fdot2 (fp32-accum) MLP ----------------
// (round-1 form: best measured. RULE: acc[]/acc2[] indices compile-time constant.)
__global__ void __launch_bounds__(256)
k_decoder(const __half* __restrict__ P, const __half* __restrict__ Q,
          const int* __restrict__ src, const int* __restrict__ dst,
          const float* __restrict__ attr,
          const __half2* __restrict__ w1cp,
          const __half2* __restrict__ w2p, const float* __restrict__ b2,
          const float* __restrict__ W3, const float* __restrict__ b3,
          float* __restrict__ out) {
    int e = blockIdx.x * blockDim.x + threadIdx.x;
    if (e >= N_EDGES) return;
    int s = src[e], d = dst[e];

    const float4* ap = (const float4*)(attr + (size_t)e * 16);
    float4 av0 = ap[0], av1 = ap[1], av2 = ap[2], av3 = ap[3];
    h2n a2[8];
    a2[0] = pack2(av0.x, av0.y); a2[1] = pack2(av0.z, av0.w);
    a2[2] = pack2(av1.x, av1.y); a2[3] = pack2(av1.z, av1.w);
    a2[4] = pack2(av2.x, av2.y); a2[5] = pack2(av2.z, av2.w);
    a2[6] = pack2(av3.x, av3.y); a2[7] = pack2(av3.z, av3.w);

    // acc = P[s] + Q[d] (fp16 rows, 128 B each: 8 x float4), fp32 accum
    float acc[64];
    const float4* Pp = (const float4*)(P + (size_t)s * 64);
    const float4* Qp = (const float4*)(Q + (size_t)d * 64);
    #pragma unroll
    for (int c = 0; c < 8; c++) {
        float4 pv = Pp[c], qv = Qp[c];
        const __half2* ph = (const __half2*)&pv;
        const __half2* qh = (const __half2*)&qv;
        #pragma unroll
        for (int u = 0; u < 4; u++) {
            float2 pf = __half22float2(ph[u]);
            float2 qf = __half22float2(qh[u]);
            acc[8 * c + 2 * u]     = pf.x + qf.x;
            acc[8 * c + 2 * u + 1] = pf.y + qf.y;
        }
    }

    // + attr @ W1c via fdot2 (k-paired): acc[j] += dot2(a2[k2], w1cp[k2*64+j])
    #pragma unroll
    for (int k2 = 0; k2 < 8; k2++) {
        #pragma unroll
        for (int j = 0; j < 64; j++)
            acc[j] = __builtin_amdgcn_fdot2(a2[k2], to_n(w1cp[k2 * 64 + j]), acc[j], false);
    }

    // relu + pack h into k-paired half2
    h2n hh[32];
    #pragma unroll
    for (int k2 = 0; k2 < 32; k2++)
        hh[k2] = pack2(fmaxf(acc[2 * k2], 0.0f), fmaxf(acc[2 * k2 + 1], 0.0f));

    // layer 2 via fdot2
    float acc2[32];
    #pragma unroll
    for (int j = 0; j < 32; j++) acc2[j] = b2[j];
    #pragma unroll
    for (int k2 = 0; k2 < 32; k2++) {
        #pragma unroll
        for (int j = 0; j < 32; j++)
            acc2[j] = __builtin_amdgcn_fdot2(hh[k2], to_n(w2p[k2 * 32 + j]), acc2[j], false);
    }

    // layer 3 (fp32)
    float o = b3[0];
    #pragma unroll
    for (int j = 0; j < 32; j++)
        o = fmaf(fmaxf(acc2[j], 0.0f), W3[j], o);
    out[e] = o;
}

// ---------------- launch ----------------
extern "C" void kernel_launch(void* const* d_in, const int* in_sizes, int n_in,
                              void* d_out, int out_size, void* d_ws, size_t ws_size,
                              hipStream_t stream) {
    const float* x      = (const float*)d_in[0];
    const int*   ei     = (const int*)d_in[1];
    const float* attr   = (const float*)d_in[2];
    const float* conv_w = (const float*)d_in[3];
    const float* conv_b = (const float*)d_in[4];
    const float* ln_g   = (const float*)d_in[5];
    const float* ln_b   = (const float*)d_in[6];
    const float* dw1    = (const float*)d_in[7];
    const float* db1    = (const float*)d_in[8];
    const float* dw2    = (const float*)d_in[9];
    const float* db2    = (const float*)d_in[10];
    const float* dw3    = (const float*)d_in[11];
    const float* db3    = (const float*)d_in[12];
    float* out = (float*)d_out;

    const int* src = ei;
    const int* dst = ei + N_EDGES;

    char* p = (char*)d_ws;
    float*   dinv    = (float*)p;   p += sizeof(float) * N_NODES;
    float*   agg     = (float*)p;   p += sizeof(float) * (size_t)N_NODES * 64;
    float*   h3      = (float*)p;   p += sizeof(float) * (size_t)N_NODES * 64;
    __half*  xs      = (__half*)p;  p += sizeof(__half) * (size_t)N_NODES * 64;
    __half*  P_h     = (__half*)p;  p += sizeof(__half) * (size_t)N_NODES * 64;
    __half*  Q_h     = (__half*)p;  p += sizeof(__half) * (size_t)N_NODES * 64;
    int*     cnt     = (int*)p;     p += sizeof(int) * N_NODES;
    int*     cursor  = (int*)p;     p += sizeof(int) * N_NODES;
    int*     cursor2 = (int*)p;     p += sizeof(int) * N_NODES;
    int*     split   = (int*)p;     p += sizeof(int) * N_NODES;
    int*     row_ptr = (int*)p;     p += sizeof(int) * (N_NODES + 1);
    int*     col     = (int*)p;     p += sizeof(int) * N_EDGES;
    int*     bsum    = (int*)p;     p += sizeof(int) * 256;
    int*     boff    = (int*)p;     p += sizeof(int) * 256;
    __half2* w1cp    = (__half2*)p; p += sizeof(__half2) * 8 * 64;
    __half2* w2p     = (__half2*)p; p += sizeof(__half2) * 32 * 32;

    const int nb_edges = (N_EDGES + 255) / 256;
    const int nb_elems = (N_NODES * 64 + 255) / 256;

    (void)hipMemsetAsync(cnt, 0, sizeof(int) * N_NODES, stream);
    k_count<<<nb_edges, 256, 0, stream>>>(src, dst, cnt);
    k_scan1<<<SCAN_BLOCKS, 256, 0, stream>>>(cnt, row_ptr, bsum, dinv);
    k_scan2_prep<<<1, 256, 0, stream>>>(bsum, boff, dw1 + 128 * 64, dw2, w1cp, w2p);
    k_scan3_xs<<<nb_elems, 256, 0, stream>>>(row_ptr, boff, cnt, cursor, cursor2,
                                             split, x, dinv, xs);
    k_fill<<<nb_edges, 256, 0, stream>>>(src, dst, cursor, cursor2, col);

    const int gemm_blocks = 1024;
    const int gather_blocks = (N_NODES * 8 + 255) / 256;   // 1 node / 8 lanes

    for (int l = 0; l < 3; l++) {
        k_gather_agg<<<gather_blocks, 256, 0, stream>>>(xs, dinv, row_ptr, split, col, agg, 0);
        k_gather_agg<<<gather_blocks, 256, 0, stream>>>(xs, dinv, row_ptr, split, col, agg, 1);
        bool last = (l == 2);
        k_gemm_ln<<<gemm_blocks, 256, 0, stream>>>(
            agg, conv_w + l * 4096, conv_b + l * 64,
            ln_g + l * 64, ln_b + l * 64, dinv,
            last ? (__half*)nullptr : xs, last ? h3 : (float*)nullptr);
    }

    // P = h3 @ W1[0:64] + b1 ; Q = h3 @ W1[64:128]  (fp16 outputs, one dispatch)
    k_gemm_pq<<<2 * gemm_blocks, 256, 0, stream>>>(h3, dw1, db1, dw1 + 64 * 64, P_h, Q_h);

    k_decoder<<<nb_edges, 256, 0, stream>>>(
        P_h, Q_h, src, dst, attr, w1cp, w2p, db2, dw3, db3, out);
}

// Round 7
// 415.741 us; speedup vs baseline: 1.1633x; 1.1633x over previous
//
#include <hip/hip_runtime.h>
#include <hip/hip_fp16.h>

#define N_NODES 50000
#define N_EDGES 800000
#define HID 64
#define F_EDGE 16
#define LN_EPS 1e-5f
#define SCAN_BLOCKS ((N_NODES + 255) / 256)   // 196

typedef _Float16 h2n __attribute__((ext_vector_type(2)));

__device__ inline h2n to_n(__half2 v) {
    union { __half2 a; h2n b; } u; u.a = v; return u.b;
}
__device__ inline h2n pack2(float x, float y) {
    h2n r; r.x = (_Float16)x; r.y = (_Float16)y; return r;
}

// ---------------- utility: 64-lane wave reduction ----------------
__device__ inline float wave_sum64(float v) {
    #pragma unroll
    for (int o = 32; o > 0; o >>= 1) v += __shfl_xor(v, o, 64);
    return v;
}

// ---------------- CSR build ----------------
__global__ void k_count(const int* __restrict__ dst, int* __restrict__ cnt) {
    int e = blockIdx.x * blockDim.x + threadIdx.x;
    if (e < N_EDGES) atomicAdd(&cnt[dst[e]], 1);
}

// stage 1: per-block exclusive scan into row_ptr, block sums into bsum; fused dinv
__global__ void k_scan1(const int* __restrict__ cnt, int* __restrict__ row_ptr,
                        int* __restrict__ bsum, float* __restrict__ dinv) {
    __shared__ int wsum[4];
    int tid = threadIdx.x, lane = tid & 63, w = tid >> 6;
    int i = blockIdx.x * 256 + tid;
    int v = (i < N_NODES) ? cnt[i] : 0;
    if (i < N_NODES) dinv[i] = rsqrtf((float)v + 1.0f);
    int isc = v;
    #pragma unroll
    for (int o = 1; o < 64; o <<= 1) {
        int n = __shfl_up(isc, o, 64);
        if (lane >= o) isc += n;
    }
    if (lane == 63) wsum[w] = isc;
    __syncthreads();
    int woff = 0;
    #pragma unroll
    for (int k = 0; k < 4; k++) woff += (k < w) ? wsum[k] : 0;
    if (i < N_NODES) row_ptr[i] = woff + isc - v;
    if (tid == 255) bsum[blockIdx.x] = woff + isc;
}

// stage 2 (+ decoder weight prep fused): single block
__global__ void k_scan2_prep(const int* __restrict__ bsum, int* __restrict__ boff,
                             const float* __restrict__ W1c, const float* __restrict__ W2,
                             __half2* __restrict__ w1cp, __half2* __restrict__ w2p) {
    __shared__ int wsum[4];
    int tid = threadIdx.x, lane = tid & 63, w = tid >> 6;
    int v = (tid < SCAN_BLOCKS) ? bsum[tid] : 0;
    int isc = v;
    #pragma unroll
    for (int o = 1; o < 64; o <<= 1) {
        int n = __shfl_up(isc, o, 64);
        if (lane >= o) isc += n;
    }
    if (lane == 63) wsum[w] = isc;
    __syncthreads();
    int woff = 0;
    #pragma unroll
    for (int k = 0; k < 4; k++) woff += (k < w) ? wsum[k] : 0;
    if (tid < SCAN_BLOCKS) boff[tid] = woff + isc - v;
    // ---- prep (independent of scan) ----
    for (int i = tid; i < 8 * 64; i += 256) {
        int k2 = i >> 6, j = i & 63;
        w1cp[i] = __floats2half2_rn(W1c[(2 * k2) * 64 + j], W1c[(2 * k2 + 1) * 64 + j]);
    }
    for (int i = tid; i < 32 * 32; i += 256) {
        int k2 = i >> 5, j = i & 31;
        w2p[i] = __floats2half2_rn(W2[(2 * k2) * 32 + j], W2[(2 * k2 + 1) * 32 + j]);
    }
}

// stage 3 (+ xs init fused): apply block offsets, init cursor; xs = fp16(dinv*x)
__global__ void k_scan3_xs(int* __restrict__ row_ptr, const int* __restrict__ boff,
                           int* __restrict__ cursor,
                           const float* __restrict__ x, const float* __restrict__ dinv,
                           __half* __restrict__ xs) {
    int i = blockIdx.x * blockDim.x + threadIdx.x;
    if (i < N_NODES) {
        int r = row_ptr[i] + boff[i >> 8];
        row_ptr[i] = r;
        cursor[i] = r;
    }
    if (i == 0) row_ptr[N_NODES] = N_EDGES;
    if (i < N_NODES * 64) xs[i] = __float2half_rn(x[i] * dinv[i >> 6]);
}

// fill: single random 4B store per edge
__global__ void k_fill(const int* __restrict__ src, const int* __restrict__ dst,
                       int* __restrict__ cursor, int* __restrict__ col) {
    int e = blockIdx.x * blockDim.x + threadIdx.x;
    if (e < N_EDGES) {
        int s = src[e], d = dst[e];
        int pos = atomicAdd(&cursor[d], 1);
        col[pos] = s;
    }
}

// ---------------- fused layer: gather + GEMM + LN in one kernel ----------------
// DOUBLE-BUFFERED: xs_in and xs_out are DIFFERENT buffers (inter-block RW race
// otherwise — round-6 lesson). Phase A (8 lanes/node, 8 nodes/wave):
// acc = di * (sum xs_in[s] + xs_in[n]) -> wave-private swizzled LDS tile.
// Phase B: per row r, GEMM (k ascending, bit-identical) + LN + relu.
// No __syncthreads: tile slice is wave-private (lgkmcnt orders w/r).
__device__ inline void row_acc(float4 raw, float m, float acc[8]) {
    const __half2* hp = (const __half2*)&raw;
    float2 f0 = __half22float2(hp[0]);
    float2 f1 = __half22float2(hp[1]);
    float2 f2 = __half22float2(hp[2]);
    float2 f3 = __half22float2(hp[3]);
    acc[0] = fmaf(f0.x, m, acc[0]); acc[1] = fmaf(f0.y, m, acc[1]);
    acc[2] = fmaf(f1.x, m, acc[2]); acc[3] = fmaf(f1.y, m, acc[3]);
    acc[4] = fmaf(f2.x, m, acc[4]); acc[5] = fmaf(f2.y, m, acc[5]);
    acc[6] = fmaf(f3.x, m, acc[6]); acc[7] = fmaf(f3.y, m, acc[7]);
}

__global__ void __launch_bounds__(256)
k_layer(const __half* __restrict__ xs_in, const float* __restrict__ dinv,
        const int* __restrict__ row_ptr, const int* __restrict__ col,
        const float* __restrict__ W, const float* __restrict__ cb,
        const float* __restrict__ gW, const float* __restrict__ bW,
        __half* __restrict__ xs_out, float* __restrict__ h_out) {
    __shared__ __align__(16) float tile[4][8 * 68];   // 4 waves x 8 rows x (64+4 pad)
    int tid = threadIdx.x;
    int wv = tid >> 6, lane = tid & 63;
    int base = (blockIdx.x * 4 + wv) * 8;             // 8 nodes per wave
    if (base >= N_NODES) return;                      // 6250 full waves exactly
    int g8 = lane >> 3;                               // node-in-group 0..7
    int c8 = lane & 7;                                // channel octet
    int n = base + g8;
    const float4* x4 = (const float4*)xs_in;

    // ---- phase A: gather ----
    float acc[8];
    {   // self-loop row
        float4 raw = x4[(size_t)n * 8 + c8];
        const __half2* hp = (const __half2*)&raw;
        float2 f0 = __half22float2(hp[0]);
        float2 f1 = __half22float2(hp[1]);
        float2 f2 = __half22float2(hp[2]);
        float2 f3 = __half22float2(hp[3]);
        acc[0] = f0.x; acc[1] = f0.y; acc[2] = f1.x; acc[3] = f1.y;
        acc[4] = f2.x; acc[5] = f2.y; acc[6] = f3.x; acc[7] = f3.y;
    }
    int beg = row_ptr[n], end = row_ptr[n + 1];
    int t = beg;
    int s0 = 0, s1 = 0, s2 = 0, s3 = 0;
    if (t < end) {
        int e1 = end - 1;
        s0 = col[t];
        s1 = col[min(t + 1, e1)];
        s2 = col[min(t + 2, e1)];
        s3 = col[min(t + 3, e1)];
    }
    while (t < end) {
        float m1 = (t + 1 < end) ? 1.0f : 0.0f;
        float m2 = (t + 2 < end) ? 1.0f : 0.0f;
        float m3 = (t + 3 < end) ? 1.0f : 0.0f;
        float4 r0 = x4[(size_t)s0 * 8 + c8];
        float4 r1 = x4[(size_t)s1 * 8 + c8];
        float4 r2 = x4[(size_t)s2 * 8 + c8];
        float4 r3 = x4[(size_t)s3 * 8 + c8];
        t += 4;
        if (t < end) {            // prefetch next quad of col entries
            int e1 = end - 1;
            s0 = col[t];
            s1 = col[min(t + 1, e1)];
            s2 = col[min(t + 2, e1)];
            s3 = col[min(t + 3, e1)];
        }
        row_acc(r0, 1.0f, acc);
        row_acc(r1, m1, acc);
        row_acc(r2, m2, acc);
        row_acc(r3, m3, acc);
    }

    // ---- write scaled row to LDS (XOR-swizzled chunks) ----
    {
        float di = dinv[n];
        float4 y0, y1;
        y0.x = acc[0] * di; y0.y = acc[1] * di; y0.z = acc[2] * di; y0.w = acc[3] * di;
        y1.x = acc[4] * di; y1.y = acc[5] * di; y1.z = acc[6] * di; y1.w = acc[7] * di;
        float4* rowv = (float4*)&tile[wv][g8 * 68];
        rowv[(2 * c8)     ^ (g8 << 1)] = y0;
        rowv[(2 * c8 + 1) ^ (g8 << 1)] = y1;
    }

    // ---- phase B: GEMM + LN for this wave's 8 rows ----
    float w[64];
    #pragma unroll
    for (int k = 0; k < 64; k++) w[k] = W[k * 64 + lane];
    float cbl = cb[lane], gl = gW[lane], bl = bW[lane];
    #pragma unroll
    for (int r = 0; r < 8; r++) {
        const float4* rw = (const float4*)&tile[wv][r * 68];
        float a = cbl;
        #pragma unroll
        for (int j = 0; j < 8; j++) {
            float4 p0 = rw[(2 * j)     ^ (r << 1)];
            float4 p1 = rw[(2 * j + 1) ^ (r << 1)];
            a = fmaf(p0.x, w[j * 8 + 0], a);
            a = fmaf(p0.y, w[j * 8 + 1], a);
            a = fmaf(p0.z, w[j * 8 + 2], a);
            a = fmaf(p0.w, w[j * 8 + 3], a);
            a = fmaf(p1.x, w[j * 8 + 4], a);
            a = fmaf(p1.y, w[j * 8 + 5], a);
            a = fmaf(p1.z, w[j * 8 + 6], a);
            a = fmaf(p1.w, w[j * 8 + 7], a);
        }
        float mu = wave_sum64(a) * (1.0f / 64.0f);
        float d = a - mu;
        float var = wave_sum64(d * d) * (1.0f / 64.0f);
        float y = fmaxf(fmaf(d * rsqrtf(var + LN_EPS), gl, bl), 0.0f);
        int nr = base + r;
        if (xs_out) {
            xs_out[nr * 64 + lane] = __float2half_rn(y * dinv[nr]);
        } else {
            h_out[nr * 64 + lane] = y;
        }
    }
}

// fused P/Q (fp16 out): first half of blocks -> P = h@W1a + b1, second half -> Q = h@W1b
__global__ void __launch_bounds__(256)
k_gemm_pq(const float* __restrict__ hin, const float* __restrict__ Wp,
          const float* __restrict__ bp, const float* __restrict__ Wq,
          __half* __restrict__ P, __half* __restrict__ Q) {
    int half_g = gridDim.x >> 1;
    bool isQ = (blockIdx.x >= half_g);
    const float* W = isQ ? Wq : Wp;
    __half* out = isQ ? Q : P;
    int lane = threadIdx.x & 63;
    int bid = isQ ? (blockIdx.x - half_g) : blockIdx.x;
    int wid = (bid * blockDim.x + threadIdx.x) >> 6;
    int nwaves = (half_g * blockDim.x) >> 6;
    float w[64];
    #pragma unroll
    for (int k = 0; k < 64; k++) w[k] = W[k * 64 + lane];
    float binit = isQ ? 0.0f : bp[lane];
    for (int row = wid; row < N_NODES; row += nwaves) {
        int r = __builtin_amdgcn_readfirstlane(row);
        const float* xr = hin + r * 64;
        float acc = binit;
        #pragma unroll
        for (int k = 0; k < 64; k++) acc = fmaf(xr[k], w[k], acc);
        out[r * 64 + lane] = __float2half_rn(acc);
    }
}

// ---------------- decoder: edge order; fp16 P/Q; fdot2 (fp32-accum) MLP ----------------
// (round-1 form: best measured. RULE: acc[]/acc2[] indices compile-time constant.)
__global__ void __launch_bounds__(256)
k_decoder(const __half* __restrict__ P, const __half* __restrict__ Q,
          const int* __restrict__ src, const int* __restrict__ dst,
          const float* __restrict__ attr,
          const __half2* __restrict__ w1cp,
          const __half2* __restrict__ w2p, const float* __restrict__ b2,
          const float* __restrict__ W3, const float* __restrict__ b3,
          float* __restrict__ out) {
    int e = blockIdx.x * blockDim.x + threadIdx.x;
    if (e >= N_EDGES) return;
    int s = src[e], d = dst[e];

    const float4* ap = (const float4*)(attr + (size_t)e * 16);
    float4 av0 = ap[0], av1 = ap[1], av2 = ap[2], av3 = ap[3];
    h2n a2[8];
    a2[0] = pack2(av0.x, av0.y); a2[1] = pack2(av0.z, av0.w);
    a2[2] = pack2(av1.x, av1.y); a2[3] = pack2(av1.z, av1.w);
    a2[4] = pack2(av2.x, av2.y); a2[5] = pack2(av2.z, av2.w);
    a2[6] = pack2(av3.x, av3.y); a2[7] = pack2(av3.z, av3.w);

    // acc = P[s] + Q[d] (fp16 rows, 128 B each: 8 x float4), fp32 accum
    float acc[64];
    const float4* Pp = (const float4*)(P + (size_t)s * 64);
    const float4* Qp = (const float4*)(Q + (size_t)d * 64);
    #pragma unroll
    for (int c = 0; c < 8; c++) {
        float4 pv = Pp[c], qv = Qp[c];
        const __half2* ph = (const __half2*)&pv;
        const __half2* qh = (const __half2*)&qv;
        #pragma unroll
        for (int u = 0; u < 4; u++) {
            float2 pf = __half22float2(ph[u]);
            float2 qf = __half22float2(qh[u]);
            acc[8 * c + 2 * u]     = pf.x + qf.x;
            acc[8 * c + 2 * u + 1] = pf.y + qf.y;
        }
    }

    // + attr @ W1c via fdot2 (k-paired): acc[j] += dot2(a2[k2], w1cp[k2*64+j])
    #pragma unroll
    for (int k2 = 0; k2 < 8; k2++) {
        #pragma unroll
        for (int j = 0; j < 64; j++)
            acc[j] = __builtin_amdgcn_fdot2(a2[k2], to_n(w1cp[k2 * 64 + j]), acc[j], false);
    }

    // relu + pack h into k-paired half2
    h2n hh[32];
    #pragma unroll
    for (int k2 = 0; k2 < 32; k2++)
        hh[k2] = pack2(fmaxf(acc[2 * k2], 0.0f), fmaxf(acc[2 * k2 + 1], 0.0f));

    // layer 2 via fdot2
    float acc2[32];
    #pragma unroll
    for (int j = 0; j < 32; j++) acc2[j] = b2[j];
    #pragma unroll
    for (int k2 = 0; k2 < 32; k2++) {
        #pragma unroll
        for (int j = 0; j < 32; j++)
            acc2[j] = __builtin_amdgcn_fdot2(hh[k2], to_n(w2p[k2 * 32 + j]), acc2[j], false);
    }

    // layer 3 (fp32)
    float o = b3[0];
    #pragma unroll
    for (int j = 0; j < 32; j++)
        o = fmaf(fmaxf(acc2[j], 0.0f), W3[j], o);
    out[e] = o;
}

// ---------------- launch ----------------
extern "C" void kernel_launch(void* const* d_in, const int* in_sizes, int n_in,
                              void* d_out, int out_size, void* d_ws, size_t ws_size,
                              hipStream_t stream) {
    const float* x      = (const float*)d_in[0];
    const int*   ei     = (const int*)d_in[1];
    const float* attr   = (const float*)d_in[2];
    const float* conv_w = (const float*)d_in[3];
    const float* conv_b = (const float*)d_in[4];
    const float* ln_g   = (const float*)d_in[5];
    const float* ln_b   = (const float*)d_in[6];
    const float* dw1    = (const float*)d_in[7];
    const float* db1    = (const float*)d_in[8];
    const float* dw2    = (const float*)d_in[9];
    const float* db2    = (const float*)d_in[10];
    const float* dw3    = (const float*)d_in[11];
    const float* db3    = (const float*)d_in[12];
    float* out = (float*)d_out;

    const int* src = ei;
    const int* dst = ei + N_EDGES;

    char* p = (char*)d_ws;
    float*   dinv    = (float*)p;   p += sizeof(float) * N_NODES;
    float*   h3      = (float*)p;   p += sizeof(float) * (size_t)N_NODES * 64;
    __half*  xs_a    = (__half*)p;  p += sizeof(__half) * (size_t)N_NODES * 64;
    __half*  xs_b    = (__half*)p;  p += sizeof(__half) * (size_t)N_NODES * 64;
    __half*  P_h     = (__half*)p;  p += sizeof(__half) * (size_t)N_NODES * 64;
    __half*  Q_h     = (__half*)p;  p += sizeof(__half) * (size_t)N_NODES * 64;
    int*     cnt     = (int*)p;     p += sizeof(int) * N_NODES;
    int*     cursor  = (int*)p;     p += sizeof(int) * N_NODES;
    int*     row_ptr = (int*)p;     p += sizeof(int) * (N_NODES + 1);
    int*     col     = (int*)p;     p += sizeof(int) * N_EDGES;
    int*     bsum    = (int*)p;     p += sizeof(int) * 256;
    int*     boff    = (int*)p;     p += sizeof(int) * 256;
    __half2* w1cp    = (__half2*)p; p += sizeof(__half2) * 8 * 64;
    __half2* w2p     = (__half2*)p; p += sizeof(__half2) * 32 * 32;

    const int nb_edges = (N_EDGES + 255) / 256;
    const int nb_elems = (N_NODES * 64 + 255) / 256;

    (void)hipMemsetAsync(cnt, 0, sizeof(int) * N_NODES, stream);
    k_count<<<nb_edges, 256, 0, stream>>>(dst, cnt);
    k_scan1<<<SCAN_BLOCKS, 256, 0, stream>>>(cnt, row_ptr, bsum, dinv);
    k_scan2_prep<<<1, 256, 0, stream>>>(bsum, boff, dw1 + 128 * 64, dw2, w1cp, w2p);
    k_scan3_xs<<<nb_elems, 256, 0, stream>>>(row_ptr, boff, cursor, x, dinv, xs_a);
    k_fill<<<nb_edges, 256, 0, stream>>>(src, dst, cursor, col);

    const int layer_blocks = (N_NODES / 8 + 3) / 4;   // 8 nodes/wave, 4 waves/block
    const int gemm_blocks = 1024;

    // layer 0: xs_a -> xs_b ; layer 1: xs_b -> xs_a ; layer 2: xs_a -> h3
    k_layer<<<layer_blocks, 256, 0, stream>>>(
        xs_a, dinv, row_ptr, col, conv_w + 0 * 4096, conv_b + 0 * 64,
        ln_g + 0 * 64, ln_b + 0 * 64, xs_b, (float*)nullptr);
    k_layer<<<layer_blocks, 256, 0, stream>>>(
        xs_b, dinv, row_ptr, col, conv_w + 1 * 4096, conv_b + 1 * 64,
        ln_g + 1 * 64, ln_b + 1 * 64, xs_a, (float*)nullptr);
    k_layer<<<layer_blocks, 256, 0, stream>>>(
        xs_a, dinv, row_ptr, col, conv_w + 2 * 4096, conv_b + 2 * 64,
        ln_g + 2 * 64, ln_b + 2 * 64, (__half*)nullptr, h3);

    // P = h3 @ W1[0:64] + b1 ; Q = h3 @ W1[64:128]  (fp16 outputs, one dispatch)
    k_gemm_pq<<<2 * gemm_blocks, 256, 0, stream>>>(h3, dw1, db1, dw1 + 64 * 64, P_h, Q_h);

    k_decoder<<<nb_edges, 256, 0, stream>>>(
        P_h, Q_h, src, dst, attr, w1cp, w2p, db2, dw3, db3, out);
}